// Round 12
// baseline (95.216 us; speedup 1.0000x reference)
//
#include <hip/hip_runtime.h>

// Problem constants (fixed shapes from setup_inputs)
constexpr int NB = 8;     // batch
constexpr int ND = 1024;  // d = 32*32 cells
constexpr int NS = 500;   // noise samples n
constexpr int NK = 16;    // k
constexpr int NC = 3;     // channels
constexpr int NH = 1024;  // H
constexpr int NW = 1024;  // W
constexpr int NP = 64;    // patch size
constexpr int PTOP = 16;  // (p - sh)/2
constexpr int PLEFT = 16; // (p - sw)/2
constexpr float SIGMA = 0.05f;

// ---- Phase 1: normalize (blocks 0-7) + zero counts (all 64 blocks) ----
__global__ void normalize_kernel(const float* __restrict__ scores,
                                 float* __restrict__ s_norm,
                                 int* __restrict__ counts) {
    int blk = blockIdx.x;   // 64 blocks
    int t = threadIdx.x;

    int4 z4 = make_int4(0, 0, 0, 0);
    ((int4*)counts)[blk * 512 + t] = z4;
    ((int4*)counts)[blk * 512 + 256 + t] = z4;

    if (blk >= NB) return;
    int b = blk;
    float v[4];
#pragma unroll
    for (int q = 0; q < 4; q++) v[q] = scores[b * ND + t + 256 * q];
    float mn = fminf(fminf(v[0], v[1]), fminf(v[2], v[3]));
    float mx = fmaxf(fmaxf(v[0], v[1]), fmaxf(v[2], v[3]));
#pragma unroll
    for (int off = 1; off < 64; off <<= 1) {
        mn = fminf(mn, __shfl_xor(mn, off));
        mx = fmaxf(mx, __shfl_xor(mx, off));
    }
    __shared__ float smn[4], smx[4];
    int wave = t >> 6, lane = t & 63;
    if (lane == 0) { smn[wave] = mn; smx[wave] = mx; }
    __syncthreads();
    mn = fminf(fminf(smn[0], smn[1]), fminf(smn[2], smn[3]));
    mx = fmaxf(fmaxf(smx[0], smx[1]), fmaxf(smx[2], smx[3]));
    float den = mx - mn + 1e-5f;
#pragma unroll
    for (int q = 0; q < 4; q++)
        s_norm[b * ND + t + 256 * q] = (v[q] - mn) / den;
}

// ---------------- Phase 2: wave-per-sample top-16 -> integer histogram ----------------
__global__ void topk_kernel(const float* __restrict__ s_norm,
                            const float* __restrict__ noise,
                            int* __restrict__ counts) {
    int t = threadIdx.x;
    int wave = t >> 6, lane = t & 63;
    int sid = blockIdx.x * 4 + wave;          // 0 .. NB*NS-1 (grid is exact)
    int b = sid / NS;

    const float* sp = s_norm + b * ND;
    const float* npp = noise + (size_t)sid * ND;

    float v[16];
#pragma unroll
    for (int q = 0; q < 16; q++) {
        int j = q * 64 + lane;
        v[q] = sp[j] + npp[j] * SIGMA;
    }

    int myj = 0x7fffffff;
    for (int it = 0; it < NK; it++) {
        float bv = v[0];
        int bq = 0;
#pragma unroll
        for (int q = 1; q < 16; q++)
            if (v[q] > bv) { bv = v[q]; bq = q; }
        int bj = bq * 64 + lane;
#pragma unroll
        for (int off = 1; off < 64; off <<= 1) {
            float ov = __shfl_xor(bv, off);
            int oj = __shfl_xor(bj, off);
            if (ov > bv || (ov == bv && oj < bj)) { bv = ov; bj = oj; }
        }
        if (lane == it) myj = bj;
        int wq = bj >> 6, wl = bj & 63;
#pragma unroll
        for (int q = 0; q < 16; q++)
            v[q] = (q == wq && lane == wl) ? -1e30f : v[q];
    }

    int rank = 0;
#pragma unroll
    for (int u = 0; u < NK; u++) {
        int other = __shfl(myj, u);
        rank += (other < myj) ? 1 : 0;
    }
    if (lane < NK)
        atomicAdd(&counts[(b * NK + rank) * ND + myj], 1);
}

// ---------------- Phase 2.5: per-batch union + per-band prefix offsets ----------------
// Entries sorted by cell (i*32+j). bandstart[b][i] = first entry with cell>=32i
// (i in [0,34); [32..33] = U). Weights: 16 f32 per entry.
__global__ void union_kernel(const int* __restrict__ counts,
                             int* __restrict__ ucell,
                             float* __restrict__ uw,
                             int* __restrict__ nunion,
                             int* __restrict__ bsg) {
    int b = blockIdx.x;
    int t = threadIdx.x;
    int lane = t & 63, wave = t >> 6;
    const int* cp = counts + b * NK * ND;

    unsigned nz = 0;
    for (int kk = 0; kk < NK; kk++) {
        int4 c4 = *(const int4*)(cp + kk * ND + t * 4);
        if (c4.x) nz |= 1;
        if (c4.y) nz |= 2;
        if (c4.z) nz |= 4;
        if (c4.w) nz |= 8;
    }
    int cnt = __popc(nz);
    int incl = cnt;
#pragma unroll
    for (int off = 1; off < 64; off <<= 1) {
        int o = __shfl_up(incl, off);
        if (lane >= off) incl += o;
    }
    int excl = incl - cnt;
    __shared__ int wtot[4];
    if (lane == 63) wtot[wave] = incl;
    __syncthreads();
    int base = 0;
    for (int w = 0; w < wave; w++) base += wtot[w];
    int pos = base + excl;

    const float invn = 1.0f / (float)NS;
    int* up = ucell + b * ND;
    float* wp = uw + (size_t)b * ND * NK;
#pragma unroll
    for (int q = 0; q < 4; q++) {
        if (nz & (1u << q)) {
            int cell = t * 4 + q;
            up[pos] = cell;
            for (int kk = 0; kk < NK; kk++)
                wp[(size_t)pos * NK + kk] = (float)cp[kk * ND + cell] * invn;
            pos++;
        }
    }
    __syncthreads();
    int U = wtot[0] + wtot[1] + wtot[2] + wtot[3];
    if (t == 0) nunion[b] = U;
    // per-band prefix offsets via binary search over the sorted cell list
    if (t < 34) {
        int thr = t * 32;      // t=32,33 -> thr >= 1024 -> lo = U
        int lo = 0, hi = U;
        while (lo < hi) {
            int mid = (lo + hi) >> 1;
            if (up[mid] < thr) lo = mid + 1; else hi = mid;
        }
        bsg[b * 34 + t] = lo;
    }
}

// ---------------- Phase 3: STREAMING gather ----------------
// Block = (bc, ypair yp in [0,32)): computes out rows {yp, yp+32}, all 16 kk.
// Needed input rows: r = 32m + zeta, zeta=(yp+16)&31, m in [0,32) — each image
// row is read by EXACTLY ONE block, as full 4-KB coalesced bursts into LDS.
// This replaces the scattered 256-B reads of R2..R10 (measured 0.4-1 TB/s
// effective on L3-cold HBM) with pure streaming (~6 TB/s).
// Rows staged in 4 chunks of 8 (33 KB, zero-padded ±16 cols -> branchless
// halo). Entries are cell-sorted; per-chunk windows come from bandstart.
// Thread (t): x=t&63, h=(t>>6)&1 (y half), kkh=t>>7 (kk half): acc[8].
// Slot mapping (derived, verified both parities):
//   h=0 (yy=yp):    d0 = (yp<16 ? 1 : 0);  entries i' in [8c+d0, 8c+8+d0), slot = i'-8c-d0
//   h=1 (yy=yp+32): d1 = (yp<16 ? 0 : -1); entries i' in [8c+d1, 8c+8+d1), slot = i'-8c-d1
// Unselected bands: their rows are skipped at stage time (uniform branch).
constexpr int WCAP = 448;   // weights LDS cap (28 KB); e >= WCAP falls back to global

__global__ void __launch_bounds__(256)
gather_kernel(const int* __restrict__ ucell,
              const float* __restrict__ uw,
              const int* __restrict__ nunion,
              const int* __restrict__ bsg,
              const float* __restrict__ x_high,
              float* __restrict__ out) {
    int blk = blockIdx.x;
    int bc = blk % 24;           // 24 % 8 == 0 -> image pinned to one XCD
    int yp = blk / 24;           // 0..31
    int b = bc / 3, c = bc % 3;
    int t = threadIdx.x;
    int x = t & 63;
    int h = (t >> 6) & 1;
    int kkh = t >> 7;

    __shared__ float ldsrow[8 * 1056];   // 33 KB: 8 slots, 16+1024+16 cols
    __shared__ float4 lw4[WCAP * 4];     // 28 KB
    __shared__ int lc[ND];               // 4 KB
    __shared__ int bsl[34];

    int U = nunion[b];
    int UC = U < WCAP ? U : WCAP;
    const float4* uwg4 = (const float4*)(uw + (size_t)b * ND * NK);

    // one-time staging: entry cells, weights, band offsets, halo zeros
    for (int i = t; i < U; i += 256) lc[i] = ucell[b * ND + i];
    for (int i = t; i < UC * 4; i += 256) lw4[i] = uwg4[i];
    if (t < 34) bsl[t] = bsg[b * 34 + t];
    {   // zero the 16-col pads of all 8 slots: 8*32 = 256 floats, 1/thread
        int slot = t >> 5, p = t & 31;
        int pos = (p < 16) ? p : (1040 + p - 16);
        ldsrow[slot * 1056 + pos] = 0.f;
    }
    __syncthreads();

    const float* xp = x_high + (size_t)bc * (NH * NW);
    int zeta = (yp + 16) & 31;
    int dh0 = (yp < 16) ? 1 : 0;
    int dh1 = (yp < 16) ? 0 : -1;
    int d = h ? dh1 : dh0;

    float acc[8];
#pragma unroll
    for (int q = 0; q < 8; q++) acc[q] = 0.f;

    for (int ch = 0; ch < 4; ch++) {
        // ---- stage 8 rows (skip rows whose bands have no entries) ----
        // q-iteration == slot (256 thr * 4 floats = exactly one 1024-f row)
#pragma unroll
        for (int q = 0; q < 8; q++) {
            int m = ch * 8 + q;
            int b0 = m + dh0, b1 = m + dh1;
            int n0 = (b0 >= 0 && b0 < 32) ? (bsl[b0 + 1] - bsl[b0]) : 0;
            int n1 = (b1 >= 0 && b1 < 32) ? (bsl[b1 + 1] - bsl[b1]) : 0;
            if ((n0 | n1) == 0) continue;          // uniform branch
            int r = m * 32 + zeta;
            int col = t * 4;
            float4 v = *(const float4*)(xp + (size_t)r * NW + col);
            *(float4*)&ldsrow[q * 1056 + 16 + col] = v;
        }
        __syncthreads();

        // ---- consume this chunk's entry window (wave-uniform h) ----
        int lob = 8 * ch + d;  if (lob < 0) lob = 0;
        int hib = 8 * ch + 8 + d;  if (hib > 32) hib = 32;
        int e0 = bsl[lob], e1 = bsl[hib];
        int base8c = 8 * ch + d;
#pragma unroll 4
        for (int e = e0; e < e1; e++) {
            int cell = lc[e];
            int slot = (cell >> 5) - base8c;
            int col16 = ((cell & 31) << 5) + x;    // = 32j + x, pad absorbs halo
            float rv = ldsrow[slot * 1056 + col16];
            float4 w0, w1;
            if (e < WCAP) {
                w0 = lw4[e * 4 + kkh * 2 + 0];
                w1 = lw4[e * 4 + kkh * 2 + 1];
            } else {
                w0 = uwg4[e * 4 + kkh * 2 + 0];
                w1 = uwg4[e * 4 + kkh * 2 + 1];
            }
            acc[0] += w0.x * rv; acc[1] += w0.y * rv;
            acc[2] += w0.z * rv; acc[3] += w0.w * rv;
            acc[4] += w1.x * rv; acc[5] += w1.y * rv;
            acc[6] += w1.z * rv; acc[7] += w1.w * rv;
        }
        __syncthreads();
    }

    int yy = yp + 32 * h;
#pragma unroll
    for (int q = 0; q < 8; q++) {
        int kk = kkh * 8 + q;
        out[((size_t)(b * NK + kk) * NC + c) * (NP * NP) + yy * NP + x] = acc[q];
    }
}

extern "C" void kernel_launch(void* const* d_in, const int* in_sizes, int n_in,
                              void* d_out, int out_size, void* d_ws, size_t ws_size,
                              hipStream_t stream) {
    const float* scores = (const float*)d_in[0];
    const float* x_high = (const float*)d_in[1];
    const float* noise  = (const float*)d_in[2];

    char* ws = (char*)d_ws;
    float* s_norm = (float*)ws;                            // 32 KB
    int* counts   = (int*)(ws + 32 * 1024);                // 512 KB (int4-aligned)
    int* ucell    = (int*)(ws + 544 * 1024);               // 32 KB
    float* uw     = (float*)(ws + 576 * 1024);             // 512 KB
    int* nunion   = (int*)(ws + 1088 * 1024);              // 32 B
    int* bsg      = (int*)(ws + 1088 * 1024 + 256);        // 8*34 ints

    normalize_kernel<<<64, 256, 0, stream>>>(scores, s_norm, counts);
    topk_kernel<<<NB * NS / 4, 256, 0, stream>>>(s_norm, noise, counts);
    union_kernel<<<NB, 256, 0, stream>>>(counts, ucell, uw, nunion, bsg);
    gather_kernel<<<24 * 32, 256, 0, stream>>>(ucell, uw, nunion, bsg, x_high,
                                               (float*)d_out);
}

// Round 13
// 69.862 us; speedup vs baseline: 1.3629x; 1.3629x over previous
//
#include <hip/hip_runtime.h>

// Problem constants (fixed shapes from setup_inputs)
constexpr int NB = 8;     // batch
constexpr int ND = 1024;  // d = 32*32 cells
constexpr int NS = 500;   // noise samples n
constexpr int NK = 16;    // k
constexpr int NC = 3;     // channels
constexpr int NH = 1024;  // H
constexpr int NW = 1024;  // W
constexpr int NP = 64;    // patch size
constexpr int PTOP = 16;  // (p - sh)/2
constexpr int PLEFT = 16; // (p - sw)/2
constexpr float SIGMA = 0.05f;

// ---- Phase 1: normalize (blocks 0-7) + zero counts (all 64 blocks) ----
__global__ void normalize_kernel(const float* __restrict__ scores,
                                 float* __restrict__ s_norm,
                                 int* __restrict__ counts) {
    int blk = blockIdx.x;   // 64 blocks
    int t = threadIdx.x;

    int4 z4 = make_int4(0, 0, 0, 0);
    ((int4*)counts)[blk * 512 + t] = z4;
    ((int4*)counts)[blk * 512 + 256 + t] = z4;

    if (blk >= NB) return;
    int b = blk;
    float v[4];
#pragma unroll
    for (int q = 0; q < 4; q++) v[q] = scores[b * ND + t + 256 * q];
    float mn = fminf(fminf(v[0], v[1]), fminf(v[2], v[3]));
    float mx = fmaxf(fmaxf(v[0], v[1]), fmaxf(v[2], v[3]));
#pragma unroll
    for (int off = 1; off < 64; off <<= 1) {
        mn = fminf(mn, __shfl_xor(mn, off));
        mx = fmaxf(mx, __shfl_xor(mx, off));
    }
    __shared__ float smn[4], smx[4];
    int wave = t >> 6, lane = t & 63;
    if (lane == 0) { smn[wave] = mn; smx[wave] = mx; }
    __syncthreads();
    mn = fminf(fminf(smn[0], smn[1]), fminf(smn[2], smn[3]));
    mx = fmaxf(fmaxf(smx[0], smx[1]), fmaxf(smx[2], smx[3]));
    float den = mx - mn + 1e-5f;
#pragma unroll
    for (int q = 0; q < 4; q++)
        s_norm[b * ND + t + 256 * q] = (v[q] - mn) / den;
}

// ---------------- Phase 2: wave-per-sample top-16 -> integer histogram ----------------
__global__ void topk_kernel(const float* __restrict__ s_norm,
                            const float* __restrict__ noise,
                            int* __restrict__ counts) {
    int t = threadIdx.x;
    int wave = t >> 6, lane = t & 63;
    int sid = blockIdx.x * 4 + wave;          // 0 .. NB*NS-1 (grid is exact)
    int b = sid / NS;

    const float* sp = s_norm + b * ND;
    const float* npp = noise + (size_t)sid * ND;

    float v[16];
#pragma unroll
    for (int q = 0; q < 16; q++) {
        int j = q * 64 + lane;
        v[q] = sp[j] + npp[j] * SIGMA;
    }

    int myj = 0x7fffffff;
    for (int it = 0; it < NK; it++) {
        float bv = v[0];
        int bq = 0;
#pragma unroll
        for (int q = 1; q < 16; q++)
            if (v[q] > bv) { bv = v[q]; bq = q; }
        int bj = bq * 64 + lane;
#pragma unroll
        for (int off = 1; off < 64; off <<= 1) {
            float ov = __shfl_xor(bv, off);
            int oj = __shfl_xor(bj, off);
            if (ov > bv || (ov == bv && oj < bj)) { bv = ov; bj = oj; }
        }
        if (lane == it) myj = bj;
        int wq = bj >> 6, wl = bj & 63;
#pragma unroll
        for (int q = 0; q < 16; q++)
            v[q] = (q == wq && lane == wl) ? -1e30f : v[q];
    }

    int rank = 0;
#pragma unroll
    for (int u = 0; u < NK; u++) {
        int other = __shfl(myj, u);
        rank += (other < myj) ? 1 : 0;
    }
    if (lane < NK)
        atomicAdd(&counts[(b * NK + rank) * ND + myj], 1);
}

// ---------------- Phase 2.5: per-batch union, quad-transposed weights ----------------
// Entry word = (i<<15)|(j<<5) == base flat index of the cell's patch origin
// (row 32i, col 32j) in the image. Weights stored TRANSPOSED per kk-quad:
// wqt[((b*4+q)*ND + e)*4 + r] = counts[(q*4+r)]/500 -> the gather reads a
// 16B-per-entry SEQUENTIAL scalar stream (3.4 KB per (b,quad): K$-resident).
__global__ void union_kernel(const int* __restrict__ counts,
                             int* __restrict__ ucell,
                             float* __restrict__ wqt,
                             int* __restrict__ nunion) {
    int b = blockIdx.x;
    int t = threadIdx.x;
    int lane = t & 63, wave = t >> 6;
    const int* cp = counts + b * NK * ND;

    unsigned nz = 0;
    for (int kk = 0; kk < NK; kk++) {
        int4 c4 = *(const int4*)(cp + kk * ND + t * 4);
        if (c4.x) nz |= 1;
        if (c4.y) nz |= 2;
        if (c4.z) nz |= 4;
        if (c4.w) nz |= 8;
    }
    int cnt = __popc(nz);
    int incl = cnt;
#pragma unroll
    for (int off = 1; off < 64; off <<= 1) {
        int o = __shfl_up(incl, off);
        if (lane >= off) incl += o;
    }
    int excl = incl - cnt;
    __shared__ int wtot[4];
    if (lane == 63) wtot[wave] = incl;
    __syncthreads();
    int base = 0;
    for (int w = 0; w < wave; w++) base += wtot[w];
    int pos = base + excl;

    const float invn = 1.0f / (float)NS;
    int* up = ucell + b * ND;
#pragma unroll
    for (int qq = 0; qq < 4; qq++) {
        if (nz & (1u << qq)) {
            int cell = t * 4 + qq;
            int i = cell >> 5, j = cell & 31;
            up[pos] = (i << 15) | (j << 5);
            for (int q = 0; q < 4; q++) {
                float4 w4;
                w4.x = (float)cp[(q * 4 + 0) * ND + cell] * invn;
                w4.y = (float)cp[(q * 4 + 1) * ND + cell] * invn;
                w4.z = (float)cp[(q * 4 + 2) * ND + cell] * invn;
                w4.w = (float)cp[(q * 4 + 3) * ND + cell] * invn;
                *(float4*)&wqt[((size_t)(b * 4 + q) * ND + pos) * 4] = w4;
            }
            pos++;
        }
    }
    if (t == 0) nunion[b] = wtot[0] + wtot[1] + wtot[2] + wtot[3];
}

// ---------------- Phase 3: union gather — scalar-stream tables, zero LDS ----------------
// Grid 1536: blk = y*24 + bc (bc = b*3+c; 24%8==0 -> image XCD-pinned).
// Block = one output row y; wave q = kk-quad (4 kk per wave); lane = column x.
// Per entry per lane: 1 v_add (idx = cellword + offu), 2 cndmask (guard),
// 1 global load, 4 FMA. Tables via SEQUENTIAL SCALAR streams: cell word (s_load,
// 840B/b) + weight quad (s_load_dwordx4, 3.4KB/(b,q)) -> K$-resident, SMEM pipe.
// This removes the per-entry-per-wave LDS broadcast traffic that dominated
// R3..R12 (LDS pipe is per-CU: 12-24 waves x U x 24-54cyc ~= 25-40us) and the
// R7/R8 K$ thrash (19KB stream > K$). No LDS, no barriers; 8-deep A/B load
// batching (select on ADDRESS; value select deferred to consume phase).
// Every output written exactly once; fixed per-thread sum order -> deterministic.
__global__ void __launch_bounds__(256)
gather_kernel(const int* __restrict__ ucell,
              const float* __restrict__ wqt,
              const int* __restrict__ nunion,
              const float* __restrict__ x_high,
              float* __restrict__ out) {
    int blk = blockIdx.x;
    int bc = blk % 24;
    int y  = blk / 24;           // 0..63
    int b = bc / 3, c = bc % 3;
    int t = threadIdx.x;
    int q = t >> 6;              // kk quad 0..3
    int x = t & 63;

    int U = nunion[b];
    const int* cl = ucell + b * ND;                               // scalar stream
    const float4* wq4 = (const float4*)(wqt + (size_t)(b * 4 + q) * ND * 4);
    const float* xp = x_high + (size_t)bc * (NH * NW);

    int ym = y - PTOP;           // [-16,48) uniform
    int xm = x - PLEFT;          // [-16,48) per lane
    int offu = ym * NW + xm;

    float acc0 = 0.f, acc1 = 0.f, acc2 = 0.f, acc3 = 0.f;

    int nb8 = U >> 3;
    for (int bi = 0; bi < nb8; bi++) {
        int e0 = bi * 8;
        float vv[8];
        bool ok[8];
        // phase A: 8 independent loads, guard applied to ADDRESS only
#pragma unroll
        for (int j = 0; j < 8; j++) {
            int w = cl[e0 + j];                    // s_load (uniform)
            int row = (w >> 15) * 32 + ym;         // scalar
            int col = ((w >> 5) & 31) * 32 + xm;   // vector
            bool okk = ((unsigned)row < (unsigned)NH) &
                       ((unsigned)col < (unsigned)NW);
            int idx = okk ? (w + offu) : 0;
            ok[j] = okk;
            vv[j] = xp[idx];                       // no consumer in this phase
        }
        // phase B: consume; weights via sequential s_load_dwordx4 (K$)
#pragma unroll
        for (int j = 0; j < 8; j++) {
            float v = ok[j] ? vv[j] : 0.f;
            float4 w4 = wq4[e0 + j];
            acc0 += w4.x * v; acc1 += w4.y * v;
            acc2 += w4.z * v; acc3 += w4.w * v;
        }
    }
    // tail (<8 entries)
    for (int e = nb8 * 8; e < U; e++) {
        int w = cl[e];
        int row = (w >> 15) * 32 + ym;
        int col = ((w >> 5) & 31) * 32 + xm;
        bool okk = ((unsigned)row < (unsigned)NH) &
                   ((unsigned)col < (unsigned)NW);
        int idx = okk ? (w + offu) : 0;
        float v = xp[idx];
        v = okk ? v : 0.f;
        float4 w4 = wq4[e];
        acc0 += w4.x * v; acc1 += w4.y * v;
        acc2 += w4.z * v; acc3 += w4.w * v;
    }

    size_t stride = (size_t)NC * NP * NP;
    size_t o = ((size_t)(b * NK + q * 4) * NC + c) * (NP * NP) + y * NP + x;
    out[o] = acc0;
    out[o + stride] = acc1;
    out[o + 2 * stride] = acc2;
    out[o + 3 * stride] = acc3;
}

extern "C" void kernel_launch(void* const* d_in, const int* in_sizes, int n_in,
                              void* d_out, int out_size, void* d_ws, size_t ws_size,
                              hipStream_t stream) {
    const float* scores = (const float*)d_in[0];
    const float* x_high = (const float*)d_in[1];
    const float* noise  = (const float*)d_in[2];

    char* ws = (char*)d_ws;
    float* s_norm = (float*)ws;                            // 32 KB
    int* counts   = (int*)(ws + 32 * 1024);                // 512 KB (int4-aligned)
    int* ucell    = (int*)(ws + 544 * 1024);               // 32 KB
    float* wqt    = (float*)(ws + 576 * 1024);             // 512 KB (quad-transposed)
    int* nunion   = (int*)(ws + 1088 * 1024);              // 32 B

    normalize_kernel<<<64, 256, 0, stream>>>(scores, s_norm, counts);
    topk_kernel<<<NB * NS / 4, 256, 0, stream>>>(s_norm, noise, counts);
    union_kernel<<<NB, 256, 0, stream>>>(counts, ucell, wqt, nunion);
    gather_kernel<<<24 * 64, 256, 0, stream>>>(ucell, wqt, nunion, x_high,
                                               (float*)d_out);
}